// Round 12
// baseline (320.625 us; speedup 1.0000x reference)
//
#include <hip/hip_runtime.h>
#include <hip/hip_bf16.h>
#include <math.h>

#define E_DIM    64
#define N_EMBED  1024
#define N_TOKENS 262144
#define FQCAP    32768

typedef __attribute__((ext_vector_type(8)))  short bf16x8;
typedef __attribute__((ext_vector_type(16))) float f32x16;

// ---------------------------------------------------------------------------
// Reference semantics (verified absmax 0.0 rounds 2,3,5,6,8-11): f32 numpy
// mirror:  b_j single fmaf chain ascending k;  a AVX512-pairwise;
// c_j sequential;  dist = fl(fl(a-2b)+c);  argmin first-min-wins.
// Round 12 = fused screen done right: round-11 fusion (screen writes q/in/g)
// but at launch_bounds(256,4) (round 11's (256,3) cost a resident block ->
// -22% on every counter), pair-resolve back INLINE (round-10 style; round
// 11's pair kernel was a ~25us latency tail), out_in written EARLY so its
// 64 MB drains under the whole kernel.
// ---------------------------------------------------------------------------

__device__ __forceinline__ short f2bf_bits(float f) {
    __hip_bfloat16 h = __float2bfloat16(f);
    return *reinterpret_cast<short*>(&h);
}
__device__ __forceinline__ float bfbits2f(short s) {
    unsigned int u = ((unsigned int)(unsigned short)s) << 16;
    return __uint_as_float(u);
}

// exact replica of one dist entry: d = fl(fl(a-2b)+c), b = fmaf chain asc k
__device__ __forceinline__ float exact_d(const float* __restrict__ xrow,
                                         const float* __restrict__ emb,
                                         const float* __restrict__ csum,
                                         float a, int j) {
#pragma clang fp contract(off)
    float b = 0.f;
#pragma unroll
    for (int k = 0; k < E_DIM; ++k) b = fmaf(xrow[k], emb[k * N_EMBED + j], b);
    return (a - 2.0f * b) + csum[j];
}

// a = np.sum(x*x, axis=1) replica (AVX512 pairwise), x in registers
__device__ __forceinline__ float a_np_of(const float* x) {
#pragma clang fp contract(off)
    float s[16];
#pragma unroll
    for (int i = 0; i < 16; ++i)
        s[i] = (x[i] * x[i] + x[i + 16] * x[i + 16]) +
               (x[i + 32] * x[i + 32] + x[i + 48] * x[i + 48]);
    float hh[8];
#pragma unroll
    for (int i = 0; i < 8; ++i) hh[i] = s[i] + s[i + 8];
    float uu[4];
#pragma unroll
    for (int i = 0; i < 4; ++i) uu[i] = hh[i] + hh[i + 4];
    return (uu[0] + uu[2]) + (uu[1] + uu[3]);
}

__device__ __forceinline__ bool lexless(float av, int ai, float bv, int bi) {
    return (av < bv) || (av == bv && ai < bi);
}

// merged prep: blocks 0-255: bf16 hi/lo of -2e into linear chunk layout
// [chunk][hi|lo][slot=k>>3][code][j=k&7] + embed copy + f32 transposed embT;
// blocks 256-259: c_j = sequential sum of e^2 (reference replica).
__global__ __launch_bounds__(256) void vq_prep(const float* __restrict__ emb,
                                               short* __restrict__ eTc,
                                               float* __restrict__ out_e,
                                               float* __restrict__ embT,
                                               float* __restrict__ c_out) {
    const int b = blockIdx.x;
    if (b < 256) {
        const int t = b * 256 + threadIdx.x;   // t = k*1024 + n
        const int k = t >> 10, n = t & 1023;
        float e = emb[t];
        float m2 = -2.0f * e;
        short hb = f2bf_bits(m2);
        short lb = f2bf_bits(m2 - bfbits2f(hb));
        const int chunk = n >> 7, code = n & 127, slot = k >> 3, jj = k & 7;
        const int base = chunk * 16384 + (slot * 128 + code) * 8 + jj;
        eTc[base]        = hb;
        eTc[base + 8192] = lb;
        out_e[t] = e;
        embT[n * E_DIM + k] = e;
    } else {
#pragma clang fp contract(off)
        const int j = (b - 256) * 256 + threadIdx.x;
        float e = emb[j];
        float s = e * e;
        for (int k = 1; k < E_DIM; ++k) {
            float ek = emb[k * N_EMBED + j];
            float pk = ek * ek;
            s = s + pk;
        }
        c_out[j] = s;
    }
}

// epilogue on raw acc (= c - 2b~ thanks to c-init): branchy top-3
__device__ __forceinline__ void tile_epilogue(
    const f32x16& acc, int codebase_global, int h,
    float& v1, float& v2, float& v3, int& i1, int& i2) {
#pragma unroll
    for (int r = 0; r < 16; ++r) {
        const int row = (r & 3) + 8 * (r >> 2) + 4 * h;
        const float d = acc[r];
        const int idx = codebase_global + row;
        if (d < v3) {
            if (d < v1)      { v3 = v2; v2 = v1; i2 = i1; v1 = d; i1 = idx; }
            else if (d < v2) { v3 = v2; v2 = d;  i2 = idx; }
            else             { v3 = d; }
        }
    }
}

__global__ __launch_bounds__(256, 4) void vq_screen_kernel(
    const float* __restrict__ in, const float* __restrict__ emb,
    const float* __restrict__ csum, const short* __restrict__ eTc,
    const float* __restrict__ embT,
    float* __restrict__ out_idx, float* __restrict__ out_q,
    float* __restrict__ out_in, float* __restrict__ out_g,
    unsigned int* __restrict__ qcnt, unsigned int* __restrict__ fullQ)
{
    __shared__ uint4 lds_e[2048];   // [0..1024) hi, [1024..2048) lo ; 32 KB

    const int t = threadIdx.x;
    const int wave = t >> 6, l = t & 63, col = l & 31, h = l >> 5;
    const int tok = blockIdx.x * 128 + wave * 32 + col;
    const float* xrow = in + (size_t)tok * E_DIM;
    const size_t obase = (size_t)tok * E_DIM;

    // ---- B operand (this lane's k-half): x[tok][s*16 + h*8 + j]
    float xv[4][8];
#pragma unroll
    for (int s = 0; s < 4; ++s) {
        float4 u0 = *reinterpret_cast<const float4*>(xrow + s * 16 + h * 8);
        float4 u1 = *reinterpret_cast<const float4*>(xrow + s * 16 + h * 8 + 4);
        xv[s][0] = u0.x; xv[s][1] = u0.y; xv[s][2] = u0.z; xv[s][3] = u0.w;
        xv[s][4] = u1.x; xv[s][5] = u1.y; xv[s][6] = u1.z; xv[s][7] = u1.w;
    }

    // ---- EARLY input-copy writes: pure streaming of register data; the
    // whole kernel lifetime is available to drain these 64 MB.
#pragma unroll
    for (int s = 0; s < 4; ++s) {
        const int k0 = s * 16 + h * 8;
        *reinterpret_cast<float4*>(out_in + obase + k0) =
            make_float4(xv[s][0], xv[s][1], xv[s][2], xv[s][3]);
        *reinterpret_cast<float4*>(out_in + obase + k0 + 4) =
            make_float4(xv[s][4], xv[s][5], xv[s][6], xv[s][7]);
    }

    bf16x8 bhi[4], blo[4];
    float sax_h = 0.f;
#pragma unroll
    for (int s = 0; s < 4; ++s) {
#pragma unroll
        for (int j = 0; j < 8; ++j) {
            float x = xv[s][j];
            sax_h += fabsf(x);
            short hb = f2bf_bits(x);
            bhi[s][j] = hb;
            blo[s][j] = f2bf_bits(x - bfbits2f(hb));
        }
    }
    const float sax = sax_h + __shfl_xor(sax_h, 32, 64);

    // ---- exact a (AVX512-pairwise replica) via cross-half exchange
    float a_np;
    {
#pragma clang fp contract(off)
        float sv[8];
#pragma unroll
        for (int j = 0; j < 8; ++j) {
            float p0 = xv[0][j] * xv[0][j];
            float p1 = xv[1][j] * xv[1][j];
            float p2 = xv[2][j] * xv[2][j];
            float p3 = xv[3][j] * xv[3][j];
            sv[j] = (p0 + p1) + (p2 + p3);
        }
        float hh[8];
#pragma unroll
        for (int j = 0; j < 8; ++j) hh[j] = sv[j] + __shfl_xor(sv[j], 32, 64);
        float u0 = hh[0] + hh[4], u1 = hh[1] + hh[5];
        float u2 = hh[2] + hh[6], u3 = hh[3] + hh[7];
        a_np = (u0 + u2) + (u1 + u3);
    }

    // ---- top-3 trackers on v = c - 2b~ (ascending code order, strict <)
    float v1 = 3.4e38f, v2 = 3.4e38f, v3 = 3.4e38f;
    int i1 = 0, i2 = 0;

    for (int cc = 0; cc < 8; ++cc) {
        __syncthreads();
        {   // linear 32 KB copy: coalesced global reads, linear b128 LDS writes
            const uint4* gsrc = reinterpret_cast<const uint4*>(eTc) + cc * 2048;
#pragma unroll
            for (int j = 0; j < 8; ++j) lds_e[j * 256 + t] = gsrc[j * 256 + t];
        }
        __syncthreads();

        const int cb = cc << 7;
#pragma unroll
        for (int tp = 0; tp < 2; ++tp) {
            const int c0 = tp * 64 + col;
            const int cbase = cb + tp * 64 + 4 * h;
            // acc initialized with c via MFMA C-operand (validated rounds 9-11)
            const float4 cA0 = *reinterpret_cast<const float4*>(&csum[cbase + 0]);
            const float4 cA1 = *reinterpret_cast<const float4*>(&csum[cbase + 8]);
            const float4 cA2 = *reinterpret_cast<const float4*>(&csum[cbase + 16]);
            const float4 cA3 = *reinterpret_cast<const float4*>(&csum[cbase + 24]);
            const float4 cB0 = *reinterpret_cast<const float4*>(&csum[cbase + 32]);
            const float4 cB1 = *reinterpret_cast<const float4*>(&csum[cbase + 40]);
            const float4 cB2 = *reinterpret_cast<const float4*>(&csum[cbase + 48]);
            const float4 cB3 = *reinterpret_cast<const float4*>(&csum[cbase + 56]);
            f32x16 accA, accB;
            accA[0]=cA0.x;  accA[1]=cA0.y;  accA[2]=cA0.z;  accA[3]=cA0.w;
            accA[4]=cA1.x;  accA[5]=cA1.y;  accA[6]=cA1.z;  accA[7]=cA1.w;
            accA[8]=cA2.x;  accA[9]=cA2.y;  accA[10]=cA2.z; accA[11]=cA2.w;
            accA[12]=cA3.x; accA[13]=cA3.y; accA[14]=cA3.z; accA[15]=cA3.w;
            accB[0]=cB0.x;  accB[1]=cB0.y;  accB[2]=cB0.z;  accB[3]=cB0.w;
            accB[4]=cB1.x;  accB[5]=cB1.y;  accB[6]=cB1.z;  accB[7]=cB1.w;
            accB[8]=cB2.x;  accB[9]=cB2.y;  accB[10]=cB2.z; accB[11]=cB2.w;
            accB[12]=cB3.x; accB[13]=cB3.y; accB[14]=cB3.z; accB[15]=cB3.w;
#pragma unroll
            for (int s = 0; s < 4; ++s) {
                const int slot = 2 * s + h;
                bf16x8 ahA = *reinterpret_cast<const bf16x8*>(&lds_e[slot * 128 + c0]);
                bf16x8 alA = *reinterpret_cast<const bf16x8*>(&lds_e[1024 + slot * 128 + c0]);
                bf16x8 ahB = *reinterpret_cast<const bf16x8*>(&lds_e[slot * 128 + c0 + 32]);
                bf16x8 alB = *reinterpret_cast<const bf16x8*>(&lds_e[1024 + slot * 128 + c0 + 32]);
                accA = __builtin_amdgcn_mfma_f32_32x32x16_bf16(ahA, bhi[s], accA, 0, 0, 0);
                accB = __builtin_amdgcn_mfma_f32_32x32x16_bf16(ahB, bhi[s], accB, 0, 0, 0);
                accA = __builtin_amdgcn_mfma_f32_32x32x16_bf16(ahA, blo[s], accA, 0, 0, 0);
                accB = __builtin_amdgcn_mfma_f32_32x32x16_bf16(ahB, blo[s], accB, 0, 0, 0);
                accA = __builtin_amdgcn_mfma_f32_32x32x16_bf16(alA, bhi[s], accA, 0, 0, 0);
                accB = __builtin_amdgcn_mfma_f32_32x32x16_bf16(alB, bhi[s], accB, 0, 0, 0);
            }
            tile_epilogue(accA, cb + tp * 64,      h, v1, v2, v3, i1, i2);
            tile_epilogue(accB, cb + tp * 64 + 32, h, v1, v2, v3, i1, i2);
        }
    }

    // ---- merge the two k-halves; shfl_xor is symmetric -> ALL 64 lanes end
    // with identical r1/r2/r3 (so the resolve below is wave-uniform per pair)
    const float w1 = __shfl_xor(v1, 32, 64), w2 = __shfl_xor(v2, 32, 64), w3 = __shfl_xor(v3, 32, 64);
    const int   j1 = __shfl_xor(i1, 32, 64), j2 = __shfl_xor(i2, 32, 64);
    const bool bfirst = lexless(w1, j1, v1, i1);
    const float r1v = bfirst ? w1 : v1;  const int r1i = bfirst ? j1 : i1;
    const float cav = bfirst ? v1 : v2;  const int cai = bfirst ? i1 : i2;
    const float cbv = bfirst ? w2 : w1;  const int cbi = bfirst ? j2 : j1;
    const bool bsec = lexless(cbv, cbi, cav, cai);
    const float r2v = bsec ? cbv : cav;  const int r2i = bsec ? cbi : cai;
    const float r3v = bsec ? fminf(cav, bfirst ? w3 : w2)
                           : fminf(cbv, bfirst ? v2 : v3);

    // 3-pass screen err ~5e-6 + reference fl(a-2b), fl(+c) double rounding
    // (<= 6.2e-5 for a<150); 1.3x margin (verified rounds 8/10/11).
    const float thr = 8e-5f + 4e-7f * sax;
    const bool sane = (a_np < 150.f) && (sax < 128.f) && (fabsf(r1v) < 0.5f);
    int fin = r1i;
    if (sane && (r2v - r1v > thr)) {
        // certified: screen winner = reference argmin
    } else if (sane && (r3v - r1v > thr)) {
        // true argmin is one of {r1i, r2i}: inline exact pair resolve.
        // Both k-half lanes run it redundantly (identical inputs) so fin is
        // available on all 64 lanes for the fused gather below.
        const float d1 = exact_d(xrow, emb, csum, a_np, r1i);
        const float d2 = exact_d(xrow, emb, csum, a_np, r2i);
        if (d2 < d1 || (d2 == d1 && r2i < r1i)) fin = r2i;
    } else {
        if (l < 32) {   // one push per token
            const unsigned int qi = atomicAdd(qcnt, 1u);
            if (qi < FQCAP) fullQ[qi] = (unsigned int)tok;
        }
        // provisional fin = r1i; vq_full rewrites idx/q/g for these tokens
    }
    if (l < 32) out_idx[tok] = (float)fin;

    // ---- fused gather: each lane writes its k-half of q / g.
    // (g = fl(x + fl(q-x)): add/sub only, no contraction hazard.)
    {
        const float* qrow = embT + (size_t)fin * E_DIM;
#pragma unroll
        for (int s = 0; s < 4; ++s) {
            const int k0 = s * 16 + h * 8;
            const float4 q0 = *reinterpret_cast<const float4*>(qrow + k0);
            const float4 q1 = *reinterpret_cast<const float4*>(qrow + k0 + 4);
            float4 g0, g1;
            g0.x = xv[s][0] + (q0.x - xv[s][0]); g0.y = xv[s][1] + (q0.y - xv[s][1]);
            g0.z = xv[s][2] + (q0.z - xv[s][2]); g0.w = xv[s][3] + (q0.w - xv[s][3]);
            g1.x = xv[s][4] + (q1.x - xv[s][4]); g1.y = xv[s][5] + (q1.y - xv[s][5]);
            g1.z = xv[s][6] + (q1.z - xv[s][6]); g1.w = xv[s][7] + (q1.w - xv[s][7]);
            *reinterpret_cast<float4*>(out_q + obase + k0)     = q0;
            *reinterpret_cast<float4*>(out_q + obase + k0 + 4) = q1;
            *reinterpret_cast<float4*>(out_g + obase + k0)     = g0;
            *reinterpret_cast<float4*>(out_g + obase + k0 + 4) = g1;
        }
    }
}

// exact full rescan (reference replica) for 3-way ties / guard trips;
// rewrites idx, q, g for its tokens.
__global__ __launch_bounds__(256) void vq_full_kernel(
    const float* __restrict__ in, const float* __restrict__ emb,
    const float* __restrict__ embT, const float* __restrict__ csum,
    const unsigned int* __restrict__ qcnt, const unsigned int* __restrict__ fullQ,
    float* __restrict__ out_idx, float* __restrict__ out_q,
    float* __restrict__ out_g) {
#pragma clang fp contract(off)
    unsigned int nq = *qcnt;
    if (nq > FQCAP) nq = FQCAP;
    const int l = threadIdx.x & 63;
    for (unsigned int w = blockIdx.x * 4 + (threadIdx.x >> 6); w < nq; w += 1024) {
        const int tok = (int)fullQ[w];
        const float* xrow = in + (size_t)tok * E_DIM;
        float x[E_DIM];
#pragma unroll
        for (int j4 = 0; j4 < 16; ++j4) {
            const float4 u = *reinterpret_cast<const float4*>(xrow + j4 * 4);
            x[j4 * 4 + 0] = u.x; x[j4 * 4 + 1] = u.y;
            x[j4 * 4 + 2] = u.z; x[j4 * 4 + 3] = u.w;
        }
        const float a = a_np_of(x);
        const int c0 = l * 16;
        float b[16];
#pragma unroll
        for (int q = 0; q < 16; ++q) b[q] = 0.f;
        for (int k = 0; k < E_DIM; ++k) {
            const float xk = x[k];
            const float* er = emb + k * N_EMBED + c0;
#pragma unroll
            for (int q = 0; q < 16; ++q) b[q] = fmaf(xk, er[q], b[q]);
        }
        float bd = 3.4e38f; int bi = 1 << 30;
#pragma unroll
        for (int q = 0; q < 16; ++q) {
            const float d = (a - 2.0f * b[q]) + csum[c0 + q];
            if (d < bd) { bd = d; bi = c0 + q; }
        }
        for (int m = 1; m < 64; m <<= 1) {
            const float od = __shfl_xor(bd, m, 64);
            const int oi = __shfl_xor(bi, m, 64);
            if (od < bd || (od == bd && oi < bi)) { bd = od; bi = oi; }
        }
        if (l == 0) out_idx[tok] = (float)bi;
        if (l < 16) {
            const float4 qv = *reinterpret_cast<const float4*>(embT + (size_t)bi * E_DIM + l * 4);
            const float4 xq = *reinterpret_cast<const float4*>(xrow + l * 4);
            float4 g;
            g.x = xq.x + (qv.x - xq.x);
            g.y = xq.y + (qv.y - xq.y);
            g.z = xq.z + (qv.z - xq.z);
            g.w = xq.w + (qv.w - xq.w);
            *reinterpret_cast<float4*>(out_q + (size_t)tok * E_DIM + l * 4) = qv;
            *reinterpret_cast<float4*>(out_g + (size_t)tok * E_DIM + l * 4) = g;
        }
    }
}

extern "C" void kernel_launch(void* const* d_in, const int* in_sizes, int n_in,
                              void* d_out, int out_size, void* d_ws, size_t ws_size,
                              hipStream_t stream) {
    const float* in  = (const float*)d_in[0];   // [262144, 64] f32
    const float* emb = (const float*)d_in[1];   // [64, 1024]  f32

    float* out     = (float*)d_out;
    float* out_q   = out;
    float* out_in  = out + (size_t)N_TOKENS * E_DIM;
    float* out_g   = out + 2ull * N_TOKENS * E_DIM;
    float* out_idx = out + 3ull * N_TOKENS * E_DIM;
    float* out_e   = out_idx + N_TOKENS;

    unsigned char* ws = (unsigned char*)d_ws;
    float*          c_ws  = (float*)(ws);                          // 4 KB
    short*          eTc   = (short*)(ws + 4096);                   // 256 KB
    float*          embT  = (float*)(ws + 4096 + 262144);          // 256 KB
    unsigned int*   qcnt  = (unsigned int*)(ws + 4096 + 262144 + 262144);  // 256 B
    unsigned int*   fullQ = (unsigned int*)(ws + 4096 + 262144 + 262144 + 256); // 128 KB

    hipMemsetAsync(qcnt, 0, sizeof(unsigned int), stream);

    vq_prep<<<260, 256, 0, stream>>>(emb, eTc, out_e, embT, c_ws);

    vq_screen_kernel<<<N_TOKENS / 128, 256, 0, stream>>>(
        in, emb, c_ws, eTc, embT, out_idx, out_q, out_in, out_g, qcnt, fullQ);

    vq_full_kernel<<<256, 256, 0, stream>>>(
        in, emb, embT, c_ws, qcnt, fullQ, out_idx, out_q, out_g);
}

// Round 13
// 287.807 us; speedup vs baseline: 1.1140x; 1.1140x over previous
//
#include <hip/hip_runtime.h>
#include <hip/hip_bf16.h>
#include <math.h>

#define E_DIM    64
#define N_EMBED  1024
#define N_TOKENS 262144
#define FQCAP    32768

typedef __attribute__((ext_vector_type(8)))  short bf16x8;
typedef __attribute__((ext_vector_type(16))) float f32x16;

// ---------------------------------------------------------------------------
// Reference semantics (verified absmax 0.0 rounds 2,3,5,6,8-12): f32 numpy
// mirror:  b_j single fmaf chain ascending k;  a AVX512-pairwise;
// c_j sequential;  dist = fl(fl(a-2b)+c);  argmin first-min-wins.
// Round 13 = round-12 fused screen with the SPILL fixed: xv dies after the
// early out_in write + operand build; the fused q/g epilogue RE-READS x from
// `in` behind a compiler memory barrier (L3-hot). Round 12's +80 MB
// symmetric FETCH/WRITE excess was xv[4][8] spilling when held live across
// the main loop at (256,4)'s 64-VGPR allocation.
// ---------------------------------------------------------------------------

__device__ __forceinline__ short f2bf_bits(float f) {
    __hip_bfloat16 h = __float2bfloat16(f);
    return *reinterpret_cast<short*>(&h);
}
__device__ __forceinline__ float bfbits2f(short s) {
    unsigned int u = ((unsigned int)(unsigned short)s) << 16;
    return __uint_as_float(u);
}

// exact replica of one dist entry: d = fl(fl(a-2b)+c), b = fmaf chain asc k
__device__ __forceinline__ float exact_d(const float* __restrict__ xrow,
                                         const float* __restrict__ emb,
                                         const float* __restrict__ csum,
                                         float a, int j) {
#pragma clang fp contract(off)
    float b = 0.f;
#pragma unroll
    for (int k = 0; k < E_DIM; ++k) b = fmaf(xrow[k], emb[k * N_EMBED + j], b);
    return (a - 2.0f * b) + csum[j];
}

// a = np.sum(x*x, axis=1) replica (AVX512 pairwise), x in registers
__device__ __forceinline__ float a_np_of(const float* x) {
#pragma clang fp contract(off)
    float s[16];
#pragma unroll
    for (int i = 0; i < 16; ++i)
        s[i] = (x[i] * x[i] + x[i + 16] * x[i + 16]) +
               (x[i + 32] * x[i + 32] + x[i + 48] * x[i + 48]);
    float hh[8];
#pragma unroll
    for (int i = 0; i < 8; ++i) hh[i] = s[i] + s[i + 8];
    float uu[4];
#pragma unroll
    for (int i = 0; i < 4; ++i) uu[i] = hh[i] + hh[i + 4];
    return (uu[0] + uu[2]) + (uu[1] + uu[3]);
}

__device__ __forceinline__ bool lexless(float av, int ai, float bv, int bi) {
    return (av < bv) || (av == bv && ai < bi);
}

// merged prep: blocks 0-255: bf16 hi/lo of -2e into linear chunk layout
// [chunk][hi|lo][slot=k>>3][code][j=k&7] + embed copy + f32 transposed embT;
// blocks 256-259: c_j = sequential sum of e^2 (reference replica).
__global__ __launch_bounds__(256) void vq_prep(const float* __restrict__ emb,
                                               short* __restrict__ eTc,
                                               float* __restrict__ out_e,
                                               float* __restrict__ embT,
                                               float* __restrict__ c_out) {
    const int b = blockIdx.x;
    if (b < 256) {
        const int t = b * 256 + threadIdx.x;   // t = k*1024 + n
        const int k = t >> 10, n = t & 1023;
        float e = emb[t];
        float m2 = -2.0f * e;
        short hb = f2bf_bits(m2);
        short lb = f2bf_bits(m2 - bfbits2f(hb));
        const int chunk = n >> 7, code = n & 127, slot = k >> 3, jj = k & 7;
        const int base = chunk * 16384 + (slot * 128 + code) * 8 + jj;
        eTc[base]        = hb;
        eTc[base + 8192] = lb;
        out_e[t] = e;
        embT[n * E_DIM + k] = e;
    } else {
#pragma clang fp contract(off)
        const int j = (b - 256) * 256 + threadIdx.x;
        float e = emb[j];
        float s = e * e;
        for (int k = 1; k < E_DIM; ++k) {
            float ek = emb[k * N_EMBED + j];
            float pk = ek * ek;
            s = s + pk;
        }
        c_out[j] = s;
    }
}

// epilogue on raw acc (= c - 2b~ thanks to c-init): branchy top-3
__device__ __forceinline__ void tile_epilogue(
    const f32x16& acc, int codebase_global, int h,
    float& v1, float& v2, float& v3, int& i1, int& i2) {
#pragma unroll
    for (int r = 0; r < 16; ++r) {
        const int row = (r & 3) + 8 * (r >> 2) + 4 * h;
        const float d = acc[r];
        const int idx = codebase_global + row;
        if (d < v3) {
            if (d < v1)      { v3 = v2; v2 = v1; i2 = i1; v1 = d; i1 = idx; }
            else if (d < v2) { v3 = v2; v2 = d;  i2 = idx; }
            else             { v3 = d; }
        }
    }
}

__global__ __launch_bounds__(256, 4) void vq_screen_kernel(
    const float* __restrict__ in, const float* __restrict__ emb,
    const float* __restrict__ csum, const short* __restrict__ eTc,
    const float* __restrict__ embT,
    float* __restrict__ out_idx, float* __restrict__ out_q,
    float* __restrict__ out_in, float* __restrict__ out_g,
    unsigned int* __restrict__ qcnt, unsigned int* __restrict__ fullQ)
{
    __shared__ uint4 lds_e[2048];   // [0..1024) hi, [1024..2048) lo ; 32 KB

    const int t = threadIdx.x;
    const int wave = t >> 6, l = t & 63, col = l & 31, h = l >> 5;
    const int tok = blockIdx.x * 128 + wave * 32 + col;
    const float* xrow = in + (size_t)tok * E_DIM;
    const size_t obase = (size_t)tok * E_DIM;

    // ---- build B operands + a/sax + early in-copy; xv DIES after this block
    bf16x8 bhi[4], blo[4];
    float sax, a_np;
    {
        float xv[4][8];
#pragma unroll
        for (int s = 0; s < 4; ++s) {
            float4 u0 = *reinterpret_cast<const float4*>(xrow + s * 16 + h * 8);
            float4 u1 = *reinterpret_cast<const float4*>(xrow + s * 16 + h * 8 + 4);
            xv[s][0] = u0.x; xv[s][1] = u0.y; xv[s][2] = u0.z; xv[s][3] = u0.w;
            xv[s][4] = u1.x; xv[s][5] = u1.y; xv[s][6] = u1.z; xv[s][7] = u1.w;
            // early input-copy writes: drain under the whole kernel
            *reinterpret_cast<float4*>(out_in + obase + s * 16 + h * 8)     = u0;
            *reinterpret_cast<float4*>(out_in + obase + s * 16 + h * 8 + 4) = u1;
        }
        float sax_h = 0.f;
#pragma unroll
        for (int s = 0; s < 4; ++s) {
#pragma unroll
            for (int j = 0; j < 8; ++j) {
                float x = xv[s][j];
                sax_h += fabsf(x);
                short hb = f2bf_bits(x);
                bhi[s][j] = hb;
                blo[s][j] = f2bf_bits(x - bfbits2f(hb));
            }
        }
        sax = sax_h + __shfl_xor(sax_h, 32, 64);
        {
#pragma clang fp contract(off)
            float sv[8];
#pragma unroll
            for (int j = 0; j < 8; ++j) {
                float p0 = xv[0][j] * xv[0][j];
                float p1 = xv[1][j] * xv[1][j];
                float p2 = xv[2][j] * xv[2][j];
                float p3 = xv[3][j] * xv[3][j];
                sv[j] = (p0 + p1) + (p2 + p3);
            }
            float hh[8];
#pragma unroll
            for (int j = 0; j < 8; ++j) hh[j] = sv[j] + __shfl_xor(sv[j], 32, 64);
            float u0 = hh[0] + hh[4], u1 = hh[1] + hh[5];
            float u2 = hh[2] + hh[6], u3 = hh[3] + hh[7];
            a_np = (u0 + u2) + (u1 + u3);
        }
    }

    // ---- top-3 trackers on v = c - 2b~ (ascending code order, strict <)
    float v1 = 3.4e38f, v2 = 3.4e38f, v3 = 3.4e38f;
    int i1 = 0, i2 = 0;

    for (int cc = 0; cc < 8; ++cc) {
        __syncthreads();
        {   // linear 32 KB copy: coalesced global reads, linear b128 LDS writes
            const uint4* gsrc = reinterpret_cast<const uint4*>(eTc) + cc * 2048;
#pragma unroll
            for (int j = 0; j < 8; ++j) lds_e[j * 256 + t] = gsrc[j * 256 + t];
        }
        __syncthreads();

        const int cb = cc << 7;
#pragma unroll
        for (int tp = 0; tp < 2; ++tp) {
            const int c0 = tp * 64 + col;
            const int cbase = cb + tp * 64 + 4 * h;
            // acc initialized with c via MFMA C-operand (validated rounds 9-12)
            const float4 cA0 = *reinterpret_cast<const float4*>(&csum[cbase + 0]);
            const float4 cA1 = *reinterpret_cast<const float4*>(&csum[cbase + 8]);
            const float4 cA2 = *reinterpret_cast<const float4*>(&csum[cbase + 16]);
            const float4 cA3 = *reinterpret_cast<const float4*>(&csum[cbase + 24]);
            const float4 cB0 = *reinterpret_cast<const float4*>(&csum[cbase + 32]);
            const float4 cB1 = *reinterpret_cast<const float4*>(&csum[cbase + 40]);
            const float4 cB2 = *reinterpret_cast<const float4*>(&csum[cbase + 48]);
            const float4 cB3 = *reinterpret_cast<const float4*>(&csum[cbase + 56]);
            f32x16 accA, accB;
            accA[0]=cA0.x;  accA[1]=cA0.y;  accA[2]=cA0.z;  accA[3]=cA0.w;
            accA[4]=cA1.x;  accA[5]=cA1.y;  accA[6]=cA1.z;  accA[7]=cA1.w;
            accA[8]=cA2.x;  accA[9]=cA2.y;  accA[10]=cA2.z; accA[11]=cA2.w;
            accA[12]=cA3.x; accA[13]=cA3.y; accA[14]=cA3.z; accA[15]=cA3.w;
            accB[0]=cB0.x;  accB[1]=cB0.y;  accB[2]=cB0.z;  accB[3]=cB0.w;
            accB[4]=cB1.x;  accB[5]=cB1.y;  accB[6]=cB1.z;  accB[7]=cB1.w;
            accB[8]=cB2.x;  accB[9]=cB2.y;  accB[10]=cB2.z; accB[11]=cB2.w;
            accB[12]=cB3.x; accB[13]=cB3.y; accB[14]=cB3.z; accB[15]=cB3.w;
#pragma unroll
            for (int s = 0; s < 4; ++s) {
                const int slot = 2 * s + h;
                bf16x8 ahA = *reinterpret_cast<const bf16x8*>(&lds_e[slot * 128 + c0]);
                bf16x8 alA = *reinterpret_cast<const bf16x8*>(&lds_e[1024 + slot * 128 + c0]);
                bf16x8 ahB = *reinterpret_cast<const bf16x8*>(&lds_e[slot * 128 + c0 + 32]);
                bf16x8 alB = *reinterpret_cast<const bf16x8*>(&lds_e[1024 + slot * 128 + c0 + 32]);
                accA = __builtin_amdgcn_mfma_f32_32x32x16_bf16(ahA, bhi[s], accA, 0, 0, 0);
                accB = __builtin_amdgcn_mfma_f32_32x32x16_bf16(ahB, bhi[s], accB, 0, 0, 0);
                accA = __builtin_amdgcn_mfma_f32_32x32x16_bf16(ahA, blo[s], accA, 0, 0, 0);
                accB = __builtin_amdgcn_mfma_f32_32x32x16_bf16(ahB, blo[s], accB, 0, 0, 0);
                accA = __builtin_amdgcn_mfma_f32_32x32x16_bf16(alA, bhi[s], accA, 0, 0, 0);
                accB = __builtin_amdgcn_mfma_f32_32x32x16_bf16(alB, bhi[s], accB, 0, 0, 0);
            }
            tile_epilogue(accA, cb + tp * 64,      h, v1, v2, v3, i1, i2);
            tile_epilogue(accB, cb + tp * 64 + 32, h, v1, v2, v3, i1, i2);
        }
    }

    // ---- merge the two k-halves; shfl_xor is symmetric -> ALL 64 lanes end
    // with identical r1/r2/r3 (resolve below is wave-uniform per token)
    const float w1 = __shfl_xor(v1, 32, 64), w2 = __shfl_xor(v2, 32, 64), w3 = __shfl_xor(v3, 32, 64);
    const int   j1 = __shfl_xor(i1, 32, 64), j2 = __shfl_xor(i2, 32, 64);
    const bool bfirst = lexless(w1, j1, v1, i1);
    const float r1v = bfirst ? w1 : v1;  const int r1i = bfirst ? j1 : i1;
    const float cav = bfirst ? v1 : v2;  const int cai = bfirst ? i1 : i2;
    const float cbv = bfirst ? w2 : w1;  const int cbi = bfirst ? j2 : j1;
    const bool bsec = lexless(cbv, cbi, cav, cai);
    const float r2v = bsec ? cbv : cav;  const int r2i = bsec ? cbi : cai;
    const float r3v = bsec ? fminf(cav, bfirst ? w3 : w2)
                           : fminf(cbv, bfirst ? v2 : v3);

    // 3-pass screen err ~5e-6 + reference fl(a-2b), fl(+c) double rounding
    // (<= 6.2e-5 for a<150); 1.3x margin (verified rounds 8/10/11/12).
    const float thr = 8e-5f + 4e-7f * sax;
    const bool sane = (a_np < 150.f) && (sax < 128.f) && (fabsf(r1v) < 0.5f);
    int fin = r1i;
    if (sane && (r2v - r1v > thr)) {
        // certified: screen winner = reference argmin
    } else if (sane && (r3v - r1v > thr)) {
        // true argmin in {r1i, r2i}: inline exact pair resolve (wave-uniform)
        const float d1 = exact_d(xrow, emb, csum, a_np, r1i);
        const float d2 = exact_d(xrow, emb, csum, a_np, r2i);
        if (d2 < d1 || (d2 == d1 && r2i < r1i)) fin = r2i;
    } else {
        if (l < 32) {   // one push per token
            const unsigned int qi = atomicAdd(qcnt, 1u);
            if (qi < FQCAP) fullQ[qi] = (unsigned int)tok;
        }
        // provisional fin = r1i; vq_full rewrites idx/q/g for these tokens
    }
    if (l < 32) out_idx[tok] = (float)fin;

    // ---- fused gather epilogue: RE-READ x (L3-hot; barrier prevents the
    // compiler CSE-ing these loads into a live xv across the main loop).
    asm volatile("" ::: "memory");
    {
        const float* qrow = embT + (size_t)fin * E_DIM;
#pragma unroll
        for (int s = 0; s < 4; ++s) {
            const int k0 = s * 16 + h * 8;
            const float4 x0 = *reinterpret_cast<const float4*>(xrow + k0);
            const float4 x1 = *reinterpret_cast<const float4*>(xrow + k0 + 4);
            const float4 q0 = *reinterpret_cast<const float4*>(qrow + k0);
            const float4 q1 = *reinterpret_cast<const float4*>(qrow + k0 + 4);
            float4 g0, g1;
            g0.x = x0.x + (q0.x - x0.x); g0.y = x0.y + (q0.y - x0.y);
            g0.z = x0.z + (q0.z - x0.z); g0.w = x0.w + (q0.w - x0.w);
            g1.x = x1.x + (q1.x - x1.x); g1.y = x1.y + (q1.y - x1.y);
            g1.z = x1.z + (q1.z - x1.z); g1.w = x1.w + (q1.w - x1.w);
            *reinterpret_cast<float4*>(out_q + obase + k0)     = q0;
            *reinterpret_cast<float4*>(out_q + obase + k0 + 4) = q1;
            *reinterpret_cast<float4*>(out_g + obase + k0)     = g0;
            *reinterpret_cast<float4*>(out_g + obase + k0 + 4) = g1;
        }
    }
}

// exact full rescan (reference replica) for 3-way ties / guard trips;
// rewrites idx, q, g for its tokens.
__global__ __launch_bounds__(256) void vq_full_kernel(
    const float* __restrict__ in, const float* __restrict__ emb,
    const float* __restrict__ embT, const float* __restrict__ csum,
    const unsigned int* __restrict__ qcnt, const unsigned int* __restrict__ fullQ,
    float* __restrict__ out_idx, float* __restrict__ out_q,
    float* __restrict__ out_g) {
#pragma clang fp contract(off)
    unsigned int nq = *qcnt;
    if (nq > FQCAP) nq = FQCAP;
    const int l = threadIdx.x & 63;
    for (unsigned int w = blockIdx.x * 4 + (threadIdx.x >> 6); w < nq; w += 1024) {
        const int tok = (int)fullQ[w];
        const float* xrow = in + (size_t)tok * E_DIM;
        float x[E_DIM];
#pragma unroll
        for (int j4 = 0; j4 < 16; ++j4) {
            const float4 u = *reinterpret_cast<const float4*>(xrow + j4 * 4);
            x[j4 * 4 + 0] = u.x; x[j4 * 4 + 1] = u.y;
            x[j4 * 4 + 2] = u.z; x[j4 * 4 + 3] = u.w;
        }
        const float a = a_np_of(x);
        const int c0 = l * 16;
        float b[16];
#pragma unroll
        for (int q = 0; q < 16; ++q) b[q] = 0.f;
        for (int k = 0; k < E_DIM; ++k) {
            const float xk = x[k];
            const float* er = emb + k * N_EMBED + c0;
#pragma unroll
            for (int q = 0; q < 16; ++q) b[q] = fmaf(xk, er[q], b[q]);
        }
        float bd = 3.4e38f; int bi = 1 << 30;
#pragma unroll
        for (int q = 0; q < 16; ++q) {
            const float d = (a - 2.0f * b[q]) + csum[c0 + q];
            if (d < bd) { bd = d; bi = c0 + q; }
        }
        for (int m = 1; m < 64; m <<= 1) {
            const float od = __shfl_xor(bd, m, 64);
            const int oi = __shfl_xor(bi, m, 64);
            if (od < bd || (od == bd && oi < bi)) { bd = od; bi = oi; }
        }
        if (l == 0) out_idx[tok] = (float)bi;
        if (l < 16) {
            const float4 qv = *reinterpret_cast<const float4*>(embT + (size_t)bi * E_DIM + l * 4);
            const float4 xq = *reinterpret_cast<const float4*>(xrow + l * 4);
            float4 g;
            g.x = xq.x + (qv.x - xq.x);
            g.y = xq.y + (qv.y - xq.y);
            g.z = xq.z + (qv.z - xq.z);
            g.w = xq.w + (qv.w - xq.w);
            *reinterpret_cast<float4*>(out_q + (size_t)tok * E_DIM + l * 4) = qv;
            *reinterpret_cast<float4*>(out_g + (size_t)tok * E_DIM + l * 4) = g;
        }
    }
}

extern "C" void kernel_launch(void* const* d_in, const int* in_sizes, int n_in,
                              void* d_out, int out_size, void* d_ws, size_t ws_size,
                              hipStream_t stream) {
    const float* in  = (const float*)d_in[0];   // [262144, 64] f32
    const float* emb = (const float*)d_in[1];   // [64, 1024]  f32

    float* out     = (float*)d_out;
    float* out_q   = out;
    float* out_in  = out + (size_t)N_TOKENS * E_DIM;
    float* out_g   = out + 2ull * N_TOKENS * E_DIM;
    float* out_idx = out + 3ull * N_TOKENS * E_DIM;
    float* out_e   = out_idx + N_TOKENS;

    unsigned char* ws = (unsigned char*)d_ws;
    float*          c_ws  = (float*)(ws);                          // 4 KB
    short*          eTc   = (short*)(ws + 4096);                   // 256 KB
    float*          embT  = (float*)(ws + 4096 + 262144);          // 256 KB
    unsigned int*   qcnt  = (unsigned int*)(ws + 4096 + 262144 + 262144);  // 256 B
    unsigned int*   fullQ = (unsigned int*)(ws + 4096 + 262144 + 262144 + 256); // 128 KB

    hipMemsetAsync(qcnt, 0, sizeof(unsigned int), stream);

    vq_prep<<<260, 256, 0, stream>>>(emb, eTc, out_e, embT, c_ws);

    vq_screen_kernel<<<N_TOKENS / 128, 256, 0, stream>>>(
        in, emb, c_ws, eTc, embT, out_idx, out_q, out_in, out_g, qcnt, fullQ);

    vq_full_kernel<<<256, 256, 0, stream>>>(
        in, emb, embT, c_ws, qcnt, fullQ, out_idx, out_q, out_g);
}

// Round 14
// 267.528 us; speedup vs baseline: 1.1985x; 1.0758x over previous
//
#include <hip/hip_runtime.h>
#include <hip/hip_bf16.h>
#include <math.h>

#define E_DIM    64
#define N_EMBED  1024
#define N_TOKENS 262144
#define FQCAP    32768

typedef __attribute__((ext_vector_type(8)))  short bf16x8;
typedef __attribute__((ext_vector_type(16))) float f32x16;

// ---------------------------------------------------------------------------
// Reference semantics (verified absmax 0.0 rounds 2,3,5,6,8-13): f32 numpy
// mirror:  b_j single fmaf chain ascending k;  a AVX512-pairwise;
// c_j sequential;  dist = fl(fl(a-2b)+c);  argmin first-min-wins.
// Round 14 = round 10 (best measured, 273.7us) + the two residuals that the
// fusion experiments (r11-13) actually validated: (1) screen writes out_in
// during its x-load (xv live range unchanged; screen HBM only 4% busy), so
// gather writes only q+g; (2) qcnt zeroed in prep (one fewer dispatch).
// Full q/g fusion is abandoned: 4 co-live f32x16 accumulators (64 AGPRs,
// unified file) cap arch VGPRs at 64 -> the fused epilogue always spills.
// ---------------------------------------------------------------------------

__device__ __forceinline__ short f2bf_bits(float f) {
    __hip_bfloat16 h = __float2bfloat16(f);
    return *reinterpret_cast<short*>(&h);
}
__device__ __forceinline__ float bfbits2f(short s) {
    unsigned int u = ((unsigned int)(unsigned short)s) << 16;
    return __uint_as_float(u);
}

// exact replica of one dist entry: d = fl(fl(a-2b)+c), b = fmaf chain asc k
__device__ __forceinline__ float exact_d(const float* __restrict__ xrow,
                                         const float* __restrict__ emb,
                                         const float* __restrict__ csum,
                                         float a, int j) {
#pragma clang fp contract(off)
    float b = 0.f;
#pragma unroll
    for (int k = 0; k < E_DIM; ++k) b = fmaf(xrow[k], emb[k * N_EMBED + j], b);
    return (a - 2.0f * b) + csum[j];
}

// a = np.sum(x*x, axis=1) replica (AVX512 pairwise), x in registers
__device__ __forceinline__ float a_np_of(const float* x) {
#pragma clang fp contract(off)
    float s[16];
#pragma unroll
    for (int i = 0; i < 16; ++i)
        s[i] = (x[i] * x[i] + x[i + 16] * x[i + 16]) +
               (x[i + 32] * x[i + 32] + x[i + 48] * x[i + 48]);
    float hh[8];
#pragma unroll
    for (int i = 0; i < 8; ++i) hh[i] = s[i] + s[i + 8];
    float uu[4];
#pragma unroll
    for (int i = 0; i < 4; ++i) uu[i] = hh[i] + hh[i + 4];
    return (uu[0] + uu[2]) + (uu[1] + uu[3]);
}

__device__ __forceinline__ bool lexless(float av, int ai, float bv, int bi) {
    return (av < bv) || (av == bv && ai < bi);
}

// merged prep: blocks 0-255: bf16 hi/lo of -2e into linear chunk layout
// [chunk][hi|lo][slot=k>>3][code][j=k&7] + embed copy + f32 transposed embT;
// blocks 256-259: c_j = sequential sum of e^2 (reference replica).
// Block 256 thread 0 also zeroes the fallback-queue counter.
__global__ __launch_bounds__(256) void vq_prep(const float* __restrict__ emb,
                                               short* __restrict__ eTc,
                                               float* __restrict__ out_e,
                                               float* __restrict__ embT,
                                               float* __restrict__ c_out,
                                               unsigned int* __restrict__ qcnt) {
    const int b = blockIdx.x;
    if (b < 256) {
        const int t = b * 256 + threadIdx.x;   // t = k*1024 + n
        const int k = t >> 10, n = t & 1023;
        float e = emb[t];
        float m2 = -2.0f * e;
        short hb = f2bf_bits(m2);
        short lb = f2bf_bits(m2 - bfbits2f(hb));
        const int chunk = n >> 7, code = n & 127, slot = k >> 3, jj = k & 7;
        const int base = chunk * 16384 + (slot * 128 + code) * 8 + jj;
        eTc[base]        = hb;
        eTc[base + 8192] = lb;
        out_e[t] = e;
        embT[n * E_DIM + k] = e;
    } else {
#pragma clang fp contract(off)
        if (b == 256 && threadIdx.x == 0) qcnt[0] = 0;
        const int j = (b - 256) * 256 + threadIdx.x;
        float e = emb[j];
        float s = e * e;
        for (int k = 1; k < E_DIM; ++k) {
            float ek = emb[k * N_EMBED + j];
            float pk = ek * ek;
            s = s + pk;
        }
        c_out[j] = s;
    }
}

// epilogue on raw acc (= c - 2b~ thanks to c-init): branchy top-3
__device__ __forceinline__ void tile_epilogue(
    const f32x16& acc, int codebase_global, int h,
    float& v1, float& v2, float& v3, int& i1, int& i2) {
#pragma unroll
    for (int r = 0; r < 16; ++r) {
        const int row = (r & 3) + 8 * (r >> 2) + 4 * h;
        const float d = acc[r];
        const int idx = codebase_global + row;
        if (d < v3) {
            if (d < v1)      { v3 = v2; v2 = v1; i2 = i1; v1 = d; i1 = idx; }
            else if (d < v2) { v3 = v2; v2 = d;  i2 = idx; }
            else             { v3 = d; }
        }
    }
}

__global__ __launch_bounds__(256, 4) void vq_screen_kernel(
    const float* __restrict__ in, const float* __restrict__ emb,
    const float* __restrict__ csum, const short* __restrict__ eTc,
    float* __restrict__ out_idx, float* __restrict__ out_in,
    unsigned int* __restrict__ qcnt, unsigned int* __restrict__ fullQ)
{
    __shared__ uint4 lds_e[2048];   // [0..1024) hi, [1024..2048) lo ; 32 KB

    const int t = threadIdx.x;
    const int wave = t >> 6, l = t & 63, col = l & 31, h = l >> 5;
    const int tok = blockIdx.x * 128 + wave * 32 + col;
    const float* xrow = in + (size_t)tok * E_DIM;
    const size_t obase = (size_t)tok * E_DIM;

    // ---- B operand (this lane's k-half): x[tok][s*16 + h*8 + j];
    // out_in written here (validated r13: no live-range extension, writes
    // drain under the whole kernel; screen HBM was 4% busy in r10).
    float xv[4][8];
#pragma unroll
    for (int s = 0; s < 4; ++s) {
        float4 u0 = *reinterpret_cast<const float4*>(xrow + s * 16 + h * 8);
        float4 u1 = *reinterpret_cast<const float4*>(xrow + s * 16 + h * 8 + 4);
        xv[s][0] = u0.x; xv[s][1] = u0.y; xv[s][2] = u0.z; xv[s][3] = u0.w;
        xv[s][4] = u1.x; xv[s][5] = u1.y; xv[s][6] = u1.z; xv[s][7] = u1.w;
        *reinterpret_cast<float4*>(out_in + obase + s * 16 + h * 8)     = u0;
        *reinterpret_cast<float4*>(out_in + obase + s * 16 + h * 8 + 4) = u1;
    }
    bf16x8 bhi[4], blo[4];
    float sax_h = 0.f;
#pragma unroll
    for (int s = 0; s < 4; ++s) {
#pragma unroll
        for (int j = 0; j < 8; ++j) {
            float x = xv[s][j];
            sax_h += fabsf(x);
            short hb = f2bf_bits(x);
            bhi[s][j] = hb;
            blo[s][j] = f2bf_bits(x - bfbits2f(hb));
        }
    }
    const float sax = sax_h + __shfl_xor(sax_h, 32, 64);

    // ---- exact a (AVX512-pairwise replica) via cross-half exchange
    float a_np;
    {
#pragma clang fp contract(off)
        float sv[8];
#pragma unroll
        for (int j = 0; j < 8; ++j) {
            float p0 = xv[0][j] * xv[0][j];
            float p1 = xv[1][j] * xv[1][j];
            float p2 = xv[2][j] * xv[2][j];
            float p3 = xv[3][j] * xv[3][j];
            sv[j] = (p0 + p1) + (p2 + p3);
        }
        float hh[8];
#pragma unroll
        for (int j = 0; j < 8; ++j) hh[j] = sv[j] + __shfl_xor(sv[j], 32, 64);
        float u0 = hh[0] + hh[4], u1 = hh[1] + hh[5];
        float u2 = hh[2] + hh[6], u3 = hh[3] + hh[7];
        a_np = (u0 + u2) + (u1 + u3);
    }

    // ---- top-3 trackers on v = c - 2b~ (ascending code order, strict <)
    float v1 = 3.4e38f, v2 = 3.4e38f, v3 = 3.4e38f;
    int i1 = 0, i2 = 0;

    for (int cc = 0; cc < 8; ++cc) {
        __syncthreads();
        {   // linear 32 KB copy: coalesced global reads, linear b128 LDS writes
            const uint4* gsrc = reinterpret_cast<const uint4*>(eTc) + cc * 2048;
#pragma unroll
            for (int j = 0; j < 8; ++j) lds_e[j * 256 + t] = gsrc[j * 256 + t];
        }
        __syncthreads();

        const int cb = cc << 7;
#pragma unroll
        for (int tp = 0; tp < 2; ++tp) {
            const int c0 = tp * 64 + col;
            const int cbase = cb + tp * 64 + 4 * h;
            // acc initialized with c via MFMA C-operand (validated rounds 9-13)
            const float4 cA0 = *reinterpret_cast<const float4*>(&csum[cbase + 0]);
            const float4 cA1 = *reinterpret_cast<const float4*>(&csum[cbase + 8]);
            const float4 cA2 = *reinterpret_cast<const float4*>(&csum[cbase + 16]);
            const float4 cA3 = *reinterpret_cast<const float4*>(&csum[cbase + 24]);
            const float4 cB0 = *reinterpret_cast<const float4*>(&csum[cbase + 32]);
            const float4 cB1 = *reinterpret_cast<const float4*>(&csum[cbase + 40]);
            const float4 cB2 = *reinterpret_cast<const float4*>(&csum[cbase + 48]);
            const float4 cB3 = *reinterpret_cast<const float4*>(&csum[cbase + 56]);
            f32x16 accA, accB;
            accA[0]=cA0.x;  accA[1]=cA0.y;  accA[2]=cA0.z;  accA[3]=cA0.w;
            accA[4]=cA1.x;  accA[5]=cA1.y;  accA[6]=cA1.z;  accA[7]=cA1.w;
            accA[8]=cA2.x;  accA[9]=cA2.y;  accA[10]=cA2.z; accA[11]=cA2.w;
            accA[12]=cA3.x; accA[13]=cA3.y; accA[14]=cA3.z; accA[15]=cA3.w;
            accB[0]=cB0.x;  accB[1]=cB0.y;  accB[2]=cB0.z;  accB[3]=cB0.w;
            accB[4]=cB1.x;  accB[5]=cB1.y;  accB[6]=cB1.z;  accB[7]=cB1.w;
            accB[8]=cB2.x;  accB[9]=cB2.y;  accB[10]=cB2.z; accB[11]=cB2.w;
            accB[12]=cB3.x; accB[13]=cB3.y; accB[14]=cB3.z; accB[15]=cB3.w;
#pragma unroll
            for (int s = 0; s < 4; ++s) {
                const int slot = 2 * s + h;
                bf16x8 ahA = *reinterpret_cast<const bf16x8*>(&lds_e[slot * 128 + c0]);
                bf16x8 alA = *reinterpret_cast<const bf16x8*>(&lds_e[1024 + slot * 128 + c0]);
                bf16x8 ahB = *reinterpret_cast<const bf16x8*>(&lds_e[slot * 128 + c0 + 32]);
                bf16x8 alB = *reinterpret_cast<const bf16x8*>(&lds_e[1024 + slot * 128 + c0 + 32]);
                accA = __builtin_amdgcn_mfma_f32_32x32x16_bf16(ahA, bhi[s], accA, 0, 0, 0);
                accB = __builtin_amdgcn_mfma_f32_32x32x16_bf16(ahB, bhi[s], accB, 0, 0, 0);
                accA = __builtin_amdgcn_mfma_f32_32x32x16_bf16(ahA, blo[s], accA, 0, 0, 0);
                accB = __builtin_amdgcn_mfma_f32_32x32x16_bf16(ahB, blo[s], accB, 0, 0, 0);
                accA = __builtin_amdgcn_mfma_f32_32x32x16_bf16(alA, bhi[s], accA, 0, 0, 0);
                accB = __builtin_amdgcn_mfma_f32_32x32x16_bf16(alB, bhi[s], accB, 0, 0, 0);
            }
            tile_epilogue(accA, cb + tp * 64,      h, v1, v2, v3, i1, i2);
            tile_epilogue(accB, cb + tp * 64 + 32, h, v1, v2, v3, i1, i2);
        }
    }

    // ---- merge the two k-halves (lanes l and l^32 hold complementary rows)
    const float w1 = __shfl_xor(v1, 32, 64), w2 = __shfl_xor(v2, 32, 64), w3 = __shfl_xor(v3, 32, 64);
    const int   j1 = __shfl_xor(i1, 32, 64), j2 = __shfl_xor(i2, 32, 64);
    const bool bfirst = lexless(w1, j1, v1, i1);
    const float r1v = bfirst ? w1 : v1;  const int r1i = bfirst ? j1 : i1;
    const float cav = bfirst ? v1 : v2;  const int cai = bfirst ? i1 : i2;
    const float cbv = bfirst ? w2 : w1;  const int cbi = bfirst ? j2 : j1;
    const bool bsec = lexless(cbv, cbi, cav, cai);
    const float r2v = bsec ? cbv : cav;  const int r2i = bsec ? cbi : cai;
    const float r3v = bsec ? fminf(cav, bfirst ? w3 : w2)
                           : fminf(cbv, bfirst ? v2 : v3);

    if (l < 32) {
        // 3-pass screen err ~5e-6 + reference fl(a-2b), fl(+c) double
        // rounding (<= 6.2e-5 for a<150); 1.3x margin (verified r8/10-13).
        const float thr = 8e-5f + 4e-7f * sax;
        const bool sane = (a_np < 150.f) && (sax < 128.f) && (fabsf(r1v) < 0.5f);
        int fin = r1i;
        if (sane && (r2v - r1v > thr)) {
            // certified: screen winner = reference argmin
        } else if (sane && (r3v - r1v > thr)) {
            // true argmin is one of {r1i, r2i}: exact pair resolve (lex tie)
            const float d1 = exact_d(xrow, emb, csum, a_np, r1i);
            const float d2 = exact_d(xrow, emb, csum, a_np, r2i);
            if (d2 < d1 || (d2 == d1 && r2i < r1i)) fin = r2i;
        } else {
            const unsigned int qi = atomicAdd(qcnt, 1u);
            if (qi < FQCAP) fullQ[qi] = (unsigned int)tok;
            // provisional fin = r1i; fallback overwrites
        }
        out_idx[tok] = (float)fin;
    }
}

// exact full rescan (reference replica) for 3-way ties / guard trips
__global__ __launch_bounds__(256) void vq_full_kernel(
    const float* __restrict__ in, const float* __restrict__ emb,
    const float* __restrict__ csum, const unsigned int* __restrict__ qcnt,
    const unsigned int* __restrict__ fullQ, float* __restrict__ out_idx) {
#pragma clang fp contract(off)
    unsigned int nq = *qcnt;
    if (nq > FQCAP) nq = FQCAP;
    const int l = threadIdx.x & 63;
    for (unsigned int w = blockIdx.x * 4 + (threadIdx.x >> 6); w < nq; w += 1024) {
        const int tok = (int)fullQ[w];
        const float* xrow = in + (size_t)tok * E_DIM;
        float x[E_DIM];
#pragma unroll
        for (int j4 = 0; j4 < 16; ++j4) {
            const float4 u = *reinterpret_cast<const float4*>(xrow + j4 * 4);
            x[j4 * 4 + 0] = u.x; x[j4 * 4 + 1] = u.y;
            x[j4 * 4 + 2] = u.z; x[j4 * 4 + 3] = u.w;
        }
        const float a = a_np_of(x);
        const int c0 = l * 16;
        float b[16];
#pragma unroll
        for (int q = 0; q < 16; ++q) b[q] = 0.f;
        for (int k = 0; k < E_DIM; ++k) {
            const float xk = x[k];
            const float* er = emb + k * N_EMBED + c0;
#pragma unroll
            for (int q = 0; q < 16; ++q) b[q] = fmaf(xk, er[q], b[q]);
        }
        float bd = 3.4e38f; int bi = 1 << 30;
#pragma unroll
        for (int q = 0; q < 16; ++q) {
            const float d = (a - 2.0f * b[q]) + csum[c0 + q];
            if (d < bd) { bd = d; bi = c0 + q; }
        }
        for (int m = 1; m < 64; m <<= 1) {
            const float od = __shfl_xor(bd, m, 64);
            const int oi = __shfl_xor(bi, m, 64);
            if (od < bd || (od == bd && oi < bi)) { bd = od; bi = oi; }
        }
        if (l == 0) out_idx[tok] = (float)bi;
    }
}

// quantize / straight-through grad (outputs 0,2); in-copy already written by
// the screen. q gathered as one float4 from the f32 transposed embT.
__global__ __launch_bounds__(256) void vq_gather_kernel(
    const float* __restrict__ in, const float* __restrict__ embT,
    const float* __restrict__ idxf,
    float* __restrict__ out_q, float* __restrict__ out_g) {
#pragma clang fp contract(off)
    const size_t j = (size_t)blockIdx.x * 256 + threadIdx.x;  // float4 index
    const int m  = (int)(j >> 4);
    const int k0 = ((int)j & 15) * 4;
    const int idx = (int)idxf[m];

    const float4 x = reinterpret_cast<const float4*>(in)[j];
    const float4 q = *reinterpret_cast<const float4*>(&embT[(size_t)idx * E_DIM + k0]);

    float4 g;
    g.x = x.x + (q.x - x.x);
    g.y = x.y + (q.y - x.y);
    g.z = x.z + (q.z - x.z);
    g.w = x.w + (q.w - x.w);

    reinterpret_cast<float4*>(out_q)[j] = q;
    reinterpret_cast<float4*>(out_g)[j] = g;
}

extern "C" void kernel_launch(void* const* d_in, const int* in_sizes, int n_in,
                              void* d_out, int out_size, void* d_ws, size_t ws_size,
                              hipStream_t stream) {
    const float* in  = (const float*)d_in[0];   // [262144, 64] f32
    const float* emb = (const float*)d_in[1];   // [64, 1024]  f32

    float* out     = (float*)d_out;
    float* out_q   = out;
    float* out_in  = out + (size_t)N_TOKENS * E_DIM;
    float* out_g   = out + 2ull * N_TOKENS * E_DIM;
    float* out_idx = out + 3ull * N_TOKENS * E_DIM;
    float* out_e   = out_idx + N_TOKENS;

    unsigned char* ws = (unsigned char*)d_ws;
    float*          c_ws  = (float*)(ws);                          // 4 KB
    short*          eTc   = (short*)(ws + 4096);                   // 256 KB
    float*          embT  = (float*)(ws + 4096 + 262144);          // 256 KB
    unsigned int*   qcnt  = (unsigned int*)(ws + 4096 + 262144 + 262144);  // 256 B
    unsigned int*   fullQ = (unsigned int*)(ws + 4096 + 262144 + 262144 + 256); // 128 KB

    vq_prep<<<260, 256, 0, stream>>>(emb, eTc, out_e, embT, c_ws, qcnt);

    vq_screen_kernel<<<N_TOKENS / 128, 256, 0, stream>>>(
        in, emb, c_ws, eTc, out_idx, out_in, qcnt, fullQ);

    vq_full_kernel<<<256, 256, 0, stream>>>(in, emb, c_ws, qcnt, fullQ, out_idx);

    const int gather_blocks = (N_TOKENS * E_DIM / 4) / 256;        // 16384
    vq_gather_kernel<<<gather_blocks, 256, 0, stream>>>(in, embT, out_idx,
                                                        out_q, out_g);
}